// Round 4
// baseline (262.364 us; speedup 1.0000x reference)
//
#include <hip/hip_runtime.h>
#include <hip/hip_bf16.h>
#include <type_traits>

#define N_SUP 32768
#define M_Q 32768
#define H_NB 32
#define K_PTS 15
#define CIN 64
#define COUT 64
#define SIGMA_ 0.1f
#define NGROUPS 8
#define NEG_SLOPE_ 0.1f
#define GEPS 1e-5f

#define QPB 16   // queries per block
#define NWAVES 4
#define KSTEPS 30  // 960 / 32

typedef __attribute__((ext_vector_type(8))) short bf16x8;
typedef __attribute__((ext_vector_type(4))) float f32x4;
typedef __attribute__((ext_vector_type(2))) float f32x2;

__device__ __forceinline__ unsigned short f_to_bf16(float f) {
    unsigned int x = __builtin_bit_cast(unsigned int, f);
    unsigned int r = (x + 0x7fffu + ((x >> 16) & 1u)) >> 16;
    return (unsigned short)r;
}

// ---- prep 1: bf16 feature table + per-row validity in one pass ----
__global__ __launch_bounds__(256) void prep_feats_valid_kernel(
    const float* __restrict__ s_feats, unsigned short* __restrict__ featsbf,
    float* __restrict__ valid)
{
    const int row  = blockIdx.x * 4 + (threadIdx.x >> 6);
    const int lane = threadIdx.x & 63;
    float f = s_feats[row * CIN + lane];
    featsbf[row * CIN + lane] = f_to_bf16(f);
#pragma unroll
    for (int m = 1; m < 64; m <<= 1) f += __shfl_xor(f, m, 64);
    if (lane == 0) valid[row] = (f > 0.f) ? 1.f : 0.f;
}

// ---- prep 1-alt (no-ws fallback): validity only ----
__global__ __launch_bounds__(256) void prep_valid_kernel(
    const float* __restrict__ s_feats, float* __restrict__ valid)
{
    const int row  = blockIdx.x * 4 + (threadIdx.x >> 6);
    const int lane = threadIdx.x & 63;
    float f = s_feats[row * CIN + lane];
#pragma unroll
    for (int m = 1; m < 64; m <<= 1) f += __shfl_xor(f, m, 64);
    if (lane == 0) valid[row] = (f > 0.f) ? 1.f : 0.f;
}

// ---- prep 1b: per-query reciprocal neighbor count ----
__global__ __launch_bounds__(256) void prep_cnt_kernel(
    const int* __restrict__ nbr, const float* __restrict__ valid,
    float* __restrict__ rcnt)
{
    const int w = threadIdx.x >> 6, lane = threadIdx.x & 63;
    const int m = blockIdx.x * 8 + w * 2 + (lane >> 5);
    const int h = lane & 31;
    float v = valid[nbr[m * H_NB + h]];
#pragma unroll
    for (int msk = 1; msk < 32; msk <<= 1) v += __shfl_xor(v, msk, 64);
    if (h == 0) rcnt[m] = 1.f / fmaxf(v, 1.f);
}

// ---- prep 2: pack conv weights [960][64] f32 -> bf16 B-fragments ----
__global__ __launch_bounds__(256) void prep_wpack_kernel(
    const float* __restrict__ weights, unsigned short* __restrict__ wpack)
{
    const int t = blockIdx.x * 256 + threadIdx.x;
    if (t >= NWAVES * KSTEPS * 64) return;
    const int l  = t & 63;
    const int s  = (t >> 6) % KSTEPS;
    const int wt = t / (KSTEPS * 64);
    const int kp = s * 32 + ((l >> 4) << 3);
    const int d  = wt * 16 + (l & 15);
    unsigned short v[8];
#pragma unroll
    for (int j = 0; j < 8; ++j)
        v[j] = f_to_bf16(weights[(kp + j) * COUT + d]);
    uint4 u;
    u.x = (unsigned)v[0] | ((unsigned)v[1] << 16);
    u.y = (unsigned)v[2] | ((unsigned)v[3] << 16);
    u.z = (unsigned)v[4] | ((unsigned)v[5] << 16);
    u.w = (unsigned)v[6] | ((unsigned)v[7] << 16);
    *(uint4*)&wpack[t * 8] = u;
}

template <bool BF>
__global__ __launch_bounds__(256, 4) void kpconv_kernel(
    const float* __restrict__ s_feats,
    const unsigned short* __restrict__ featsbf,
    const float* __restrict__ q_points,
    const float* __restrict__ s_points,
    const int*   __restrict__ nbr_idx,
    const float* __restrict__ kpts,
    const unsigned short* __restrict__ wpack,
    const float* __restrict__ rcnt,
    const float* __restrict__ bias,
    float* __restrict__ y_out,      // d_out: pre-GN conv output [M, COUT]
    float* __restrict__ gstats)     // ws: 16 floats (sum[8], sumsq[8])
{
    __shared__ float w_lds[NWAVES][H_NB][16];            // 8 KB, single slot/wave
    __shared__ unsigned short wtd_lds[QPB][K_PTS][CIN];  // 30 KB (bf16, q-swizzled)
    __shared__ float nbr_lds[QPB];

    const int tid  = threadIdx.x;
    const int lane = tid & 63;
    const int wid  = __builtin_amdgcn_readfirstlane(tid >> 6);

    // kernel points (uniform -> scalar regs)
    float kpx[K_PTS], kpy[K_PTS], kpz[K_PTS];
#pragma unroll
    for (int k = 0; k < K_PTS; ++k) {
        kpx[k] = kpts[k * 3 + 0];
        kpy[k] = kpts[k * 3 + 1];
        kpz[k] = kpts[k * 3 + 2];
    }

    const int h1    = lane >> 1;   // phase-1: 2 lanes per neighbor
    const int khalf = lane & 1;
    const int half  = lane >> 5;   // phase-2: 0 = even h rows, 1 = odd h rows
    const int cpair = lane & 31;   // phase-2: channels {2*cpair, 2*cpair+1}
    const int mbase = blockIdx.x * QPB + wid * 4;

    // ---- prologue: ALL per-query geometry loads issued up front ----
    int h1i[4];
#pragma unroll
    for (int j = 0; j < 4; ++j)
        h1i[j] = nbr_idx[(mbase + j) * H_NB + h1];   // per-lane gather, independent x4
    float ddx[4], ddy[4], ddz[4];
#pragma unroll
    for (int j = 0; j < 4; ++j) {
        const float qx = q_points[(mbase + j) * 3 + 0];   // uniform s_loads
        const float qy = q_points[(mbase + j) * 3 + 1];
        const float qz = q_points[(mbase + j) * 3 + 2];
        ddx[j] = s_points[h1i[j] * 3 + 0] - qx;
        ddy[j] = s_points[h1i[j] * 3 + 1] - qy;
        ddz[j] = s_points[h1i[j] * 3 + 2] - qz;
    }

    using fbuf_t = typename std::conditional<BF, unsigned int, f32x2>::type;
    fbuf_t fb0[16], fb1[16];

    auto issueF = [&](int j, fbuf_t (&fb)[16]) {
#pragma unroll
        for (int t = 0; t < 16; ++t) {
            // lane (4t + 2*half) holds nbr index of h = 2t + half
            const int sidx = __shfl(h1i[j], 4 * t + 2 * half, 64);
            if constexpr (BF)
                fb[t] = *(const unsigned int*)&featsbf[sidx * CIN + cpair * 2];
            else
                fb[t] = *(const f32x2*)&s_feats[sidx * CIN + cpair * 2];
        }
    };

    auto wcomp = [&](int j) {
        float wb[8];
#pragma unroll
        for (int jj = 0; jj < 8; ++jj) {
            const int k = khalf * 8 + jj;
            float w = 0.f;
            if (k < K_PTS) {
                const float ex = ddx[j] - kpx[k];
                const float ey = ddy[j] - kpy[k];
                const float ez = ddz[j] - kpz[k];
                w = fmaxf(1.f - sqrtf(ex * ex + ey * ey + ez * ez) * (1.f / SIGMA_), 0.f);
            }
            wb[jj] = w;
        }
        *(float4*)&w_lds[wid][h1][khalf * 8 + 0] = make_float4(wb[0], wb[1], wb[2], wb[3]);
        *(float4*)&w_lds[wid][h1][khalf * 8 + 4] = make_float4(wb[4], wb[5], wb[6], wb[7]);
    };

    auto consume = [&](int j, fbuf_t (&fb)[16]) {
        const int q = wid * 4 + j;
        f32x2 acc[K_PTS];
#pragma unroll
        for (int k = 0; k < K_PTS; ++k) acc[k] = (f32x2){0.f, 0.f};
#pragma unroll
        for (int t = 0; t < 16; ++t) {
            f32x2 fv;
            if constexpr (BF) {
                const unsigned int u = fb[t];
                fv.x = __builtin_bit_cast(float, u << 16);
                fv.y = __builtin_bit_cast(float, u & 0xffff0000u);
            } else {
                fv = fb[t];
            }
            const int hh = 2 * t + half;
            const float4 w0 = *(const float4*)&w_lds[wid][hh][0];
            const float4 w1 = *(const float4*)&w_lds[wid][hh][4];
            const float4 w2 = *(const float4*)&w_lds[wid][hh][8];
            const float4 w3 = *(const float4*)&w_lds[wid][hh][12];
            acc[0]  += fv * w0.x;  acc[1]  += fv * w0.y;
            acc[2]  += fv * w0.z;  acc[3]  += fv * w0.w;
            acc[4]  += fv * w1.x;  acc[5]  += fv * w1.y;
            acc[6]  += fv * w1.z;  acc[7]  += fv * w1.w;
            acc[8]  += fv * w2.x;  acc[9]  += fv * w2.y;
            acc[10] += fv * w2.z;  acc[11] += fv * w2.w;
            acc[12] += fv * w3.x;  acc[13] += fv * w3.y;
            acc[14] += fv * w3.z;
        }
#pragma unroll
        for (int k = 0; k < K_PTS; ++k) {
            acc[k].x += __shfl_xor(acc[k].x, 32, 64);
            acc[k].y += __shfl_xor(acc[k].y, 32, 64);
        }
        const int cbase = cpair * 2;
        const int c0 = (((cbase >> 3) ^ (q & 7)) << 3) | (cbase & 7);
#pragma unroll
        for (int k = 0; k < K_PTS; ++k) {
            if ((k >> 3) == half) {
                unsigned int u;
                asm("v_cvt_pk_bf16_f32 %0, %1, %2"
                    : "=v"(u) : "v"(acc[k].x), "v"(acc[k].y));
                *(unsigned int*)&wtd_lds[q][k][c0] = u;
            }
        }
        if (lane == 0) nbr_lds[q] = rcnt[mbase + j];
    };

    // pipeline: wcomp(i); issue feats(i+1); consume(i)  — single w slot is safe
    // because consume(i)'s DS reads precede wcomp(i+1)'s DS writes in program
    // order and the per-wave DS unit is in-order.
    issueF(0, fb0);
    wcomp(0); issueF(1, fb1); consume(0, fb0);
    wcomp(1); issueF(2, fb0); consume(1, fb1);
    wcomp(2); issueF(3, fb1); consume(2, fb0);
    wcomp(3);                 consume(3, fb1);
    __syncthreads();

    // ------- phase 3: MFMA GEMM  out[16q x 64d] = wtd[16q x 960] * W -------
    {
        f32x4 acc3 = {0.f, 0.f, 0.f, 0.f};
        const int qa  = lane & 15;
        const int grp = lane >> 4;
        const unsigned short* wp = &wpack[(wid * KSTEPS) * 64 * 8 + lane * 8];
        for (int s = 0; s < KSTEPS; ++s) {
            const int k  = s >> 1;
            const int ch = (((s & 1) * 4 + grp) ^ (lane & 7));  // q-row swizzle
            bf16x8 a = *(const bf16x8*)&wtd_lds[qa][k][ch * 8];
            bf16x8 b = *(const bf16x8*)&wp[s * 512];
            acc3 = __builtin_amdgcn_mfma_f32_16x16x32_bf16(a, b, acc3, 0, 0, 0);
        }
        // epilogue: C layout col(d)=lane&15, row(q)=(lane>>4)*4+r
        const int dl = wid * 16 + (lane & 15);
        const float bv = bias[dl];
        float s1 = 0.f, s2 = 0.f;
#pragma unroll
        for (int r = 0; r < 4; ++r) {
            const int qq = grp * 4 + r;
            const float yv = acc3[r] * nbr_lds[qq] + bv;
            y_out[(blockIdx.x * QPB + qq) * COUT + dl] = yv;
            s1 += yv;
            s2 += yv * yv;
        }
        s1 += __shfl_xor(s1, 1, 64);   s2 += __shfl_xor(s2, 1, 64);
        s1 += __shfl_xor(s1, 2, 64);   s2 += __shfl_xor(s2, 2, 64);
        s1 += __shfl_xor(s1, 4, 64);   s2 += __shfl_xor(s2, 4, 64);
        s1 += __shfl_xor(s1, 16, 64);  s2 += __shfl_xor(s2, 16, 64);
        s1 += __shfl_xor(s1, 32, 64);  s2 += __shfl_xor(s2, 32, 64);
        if (lane == 0 || lane == 8) {
            const int g = wid * 2 + ((lane >> 3) & 1);
            atomicAdd(&gstats[g], s1);
            atomicAdd(&gstats[8 + g], s2);
        }
    }
}

__global__ __launch_bounds__(256) void gn_kernel(
    const float* __restrict__ gstats,
    const float* __restrict__ gamma,
    const float* __restrict__ beta,
    float* __restrict__ out)   // in-place on d_out
{
    const int idx4 = blockIdx.x * blockDim.x + threadIdx.x;
    const int d4 = idx4 & (COUT / 4 - 1);
    const int d = d4 * 4;
    const int g = d >> 3;
    const float cntinv = 1.f / (float)(M_Q * (COUT / NGROUPS));
    const float mean = gstats[g] * cntinv;
    const float var = gstats[8 + g] * cntinv - mean * mean;
    const float rs = rsqrtf(var + GEPS);
    float4 y = ((const float4*)out)[idx4];
    const float4 gm = ((const float4*)gamma)[d4];
    const float4 bt = ((const float4*)beta)[d4];
    float v;
    v = (y.x - mean) * rs * gm.x + bt.x;  y.x = v >= 0.f ? v : NEG_SLOPE_ * v;
    v = (y.y - mean) * rs * gm.y + bt.y;  y.y = v >= 0.f ? v : NEG_SLOPE_ * v;
    v = (y.z - mean) * rs * gm.z + bt.z;  y.z = v >= 0.f ? v : NEG_SLOPE_ * v;
    v = (y.w - mean) * rs * gm.w + bt.w;  y.w = v >= 0.f ? v : NEG_SLOPE_ * v;
    ((float4*)out)[idx4] = y;
}

extern "C" void kernel_launch(void* const* d_in, const int* in_sizes, int n_in,
                              void* d_out, int out_size, void* d_ws, size_t ws_size,
                              hipStream_t stream) {
    const float* s_feats  = (const float*)d_in[0];
    const float* q_points = (const float*)d_in[1];
    const float* s_points = (const float*)d_in[2];
    const int*   nbr      = (const int*)d_in[3];
    const float* kpts     = (const float*)d_in[4];
    const float* weights  = (const float*)d_in[5];
    const float* bias     = (const float*)d_in[6];
    const float* gamma    = (const float*)d_in[7];
    const float* beta     = (const float*)d_in[8];
    float* out = (float*)d_out;

    // ws layout: stats[16] | valid[N] | rcnt[M] | wpack bf16 | featsbf bf16
    float* stats = (float*)d_ws;
    float* valid = stats + 16;
    float* rcnt  = valid + N_SUP;
    unsigned short* wpack = (unsigned short*)(rcnt + M_Q);            // 61440 ush
    unsigned short* featsbf = wpack + NWAVES * KSTEPS * 64 * 8;       // 2M ush
    const size_t need_bf = (size_t)((16 + N_SUP + M_Q) * 4)
                         + (size_t)(NWAVES * KSTEPS * 64 * 8 * 2)
                         + (size_t)N_SUP * CIN * 2;
    const bool use_bf = ws_size >= need_bf;

    hipMemsetAsync(stats, 0, 16 * sizeof(float), stream);
    if (use_bf)
        prep_feats_valid_kernel<<<N_SUP / 4, 256, 0, stream>>>(s_feats, featsbf, valid);
    else
        prep_valid_kernel<<<N_SUP / 4, 256, 0, stream>>>(s_feats, valid);
    prep_cnt_kernel<<<M_Q / 8, 256, 0, stream>>>(nbr, valid, rcnt);
    prep_wpack_kernel<<<(NWAVES * KSTEPS * 64 + 255) / 256, 256, 0, stream>>>(weights, wpack);
    if (use_bf)
        kpconv_kernel<true><<<M_Q / QPB, 256, 0, stream>>>(
            s_feats, featsbf, q_points, s_points, nbr, kpts, wpack, rcnt, bias, out, stats);
    else
        kpconv_kernel<false><<<M_Q / QPB, 256, 0, stream>>>(
            s_feats, featsbf, q_points, s_points, nbr, kpts, wpack, rcnt, bias, out, stats);
    gn_kernel<<<(M_Q * COUT / 4) / 256, 256, 0, stream>>>(stats, gamma, beta, out);
}